// Round 10
// baseline (3029.210 us; speedup 1.0000x reference)
//
#include <hip/hip_runtime.h>
#include <stdint.h>

#define N      12288              // 96*128 descriptors
#define CH     512                // channels
#define TI2    256                // output tile (both dims)
#define NT2    48                 // N/256 i-tiles (and j-tiles)
#define NS2    16                 // j-slices
#define JT2    3                  // j-tiles per slice (48/16)
#define GPJ    16                 // K-steps per j-tile (BK = 32 channels)
#define NSTEP2 (JT2 * GPJ)        // 48 steps per block
#define DSMEM_BYTES (131072 + 16384 + 8192 + 2048)   // SM + rowW + colW + ia/ib

typedef _Float16 f16x8 __attribute__((ext_vector_type(8)));
typedef float    f32x4 __attribute__((ext_vector_type(4)));

struct Top2 { float v0, v1; int i0, i1; };

// ---- module-scope device scratch (graph-capture safe, rewritten every launch)
__device__ float g_invA[N];
__device__ float g_invB[N];
// split-fp16 operands, K-MAJOR: [g32][d][8 chunks of 16B], g32 = 32-channel
// group. Within each 128B row ([32 hi | 32 lo] halfs) chunk c is stored at
// physical slot c^(d&7) -> LINEAR copy into LDS yields bank-conflict-free
// ds_read_b128 fragment reads (verified: SQ_LDS_BANK_CONFLICT = 0, R4-R9).
__device__ unsigned short g_AT[(size_t)N * 1024];
__device__ unsigned short g_BT[(size_t)N * 1024];
__device__ Top2  g_rpart[NS2][N];
__device__ Top2  g_cpart[NT2][N];
__device__ int   g_nn12[N];
__device__ float g_r12[N];
__device__ float g_sim0[N];
__device__ int   g_nn21[N];
__device__ float g_r21[N];

// insert candidate (v, idx) into running top-2; ties -> lower index (lax.top_k)
__device__ __forceinline__ void t2_ins(float v, int idx,
                                       float& v0, int& i0, float& v1, int& i1) {
  bool beats0 = (v > v0) || (v == v0 && idx < i0);
  bool beats1 = (v > v1) || (v == v1 && idx < i1);
  if (beats0) { v1 = v0; i1 = i0; v0 = v; i0 = idx; }
  else if (beats1) { v1 = v; i1 = idx; }
}

__device__ __forceinline__ float bf16_quant(float f) {
  unsigned int u = __float_as_uint(f);
  unsigned int r = 0x7fffu + ((u >> 16) & 1u);
  unsigned int q = ((u + r) >> 16) << 16;
  return __uint_as_float(q);
}

// ---------------- kernel 1: transpose + split-fp16 + inverse norms ----------------
__global__ __launch_bounds__(256)
void prep_kernel(const float* __restrict__ A, const float* __restrict__ B) {
  const int d0 = blockIdx.x * 64;
  const float* src = blockIdx.y ? B : A;
  unsigned short* dst = blockIdx.y ? g_BT : g_AT;
  float* inv = blockIdx.y ? g_invB : g_invA;

  __shared__ float Ls[32][68];            // fp32 in-tile (68: 16B-aligned rows)
  __shared__ unsigned short Os[64][64];   // packed out-tile [d][32 hi|32 lo]
  __shared__ float Ps[4][64];             // norm partials

  const int t = threadIdx.x;
  const int a = t >> 6, dl = t & 63;
  float sum = 0.f;

  for (int g = 0; g < 16; ++g) {
    __syncthreads();
    {   // load [32 ch][64 d] fp32 tile, coalesced
      const int c = t >> 3, dc = (t & 7) * 8;
      const float* p = src + (size_t)(g * 32 + c) * N + d0 + dc;
      float4 v0 = *reinterpret_cast<const float4*>(p);
      float4 v1 = *reinterpret_cast<const float4*>(p + 4);
      *reinterpret_cast<float4*>(&Ls[c][dc])     = v0;
      *reinterpret_cast<float4*>(&Ls[c][dc + 4]) = v1;
    }
    __syncthreads();
    {   // split 8 channels per thread, pack into Os
      _Float16 hv[8] __attribute__((aligned(16)));
      _Float16 lv[8] __attribute__((aligned(16)));
#pragma unroll
      for (int j = 0; j < 8; ++j) {
        float v = Ls[a * 8 + j][dl] * 1024.0f;
        sum += v * v;
        _Float16 h = (_Float16)v;
        float rr = v - (float)h;          // exact in fp32
        hv[j] = h;
        lv[j] = (_Float16)rr;
      }
      *reinterpret_cast<uint4*>(&Os[dl][a * 8])      = *reinterpret_cast<const uint4*>(hv);
      *reinterpret_cast<uint4*>(&Os[dl][32 + a * 8]) = *reinterpret_cast<const uint4*>(lv);
    }
    __syncthreads();
    {   // store out-tile K-major: row d of group g, chunks XOR-swizzled
#pragma unroll
      for (int p2 = 0; p2 < 2; ++p2) {
        const int d = p2 * 32 + (t >> 3), ch = t & 7;
        const int sc = ch ^ (d & 7);      // swizzled chunk slot
        *reinterpret_cast<uint4*>((char*)dst
            + ((size_t)g * N + d0 + d) * 128 + sc * 16)
            = *reinterpret_cast<const uint4*>(&Os[d][ch * 8]);
      }
    }
  }
  Ps[a][dl] = sum;
  __syncthreads();
  if (t < 64) {
    float tot = Ps[0][t] + Ps[1][t] + Ps[2][t] + Ps[3][t];
    inv[d0 + t] = 1.0f / sqrtf(tot);
  }
}

// ---------------- kernel 2: MFMA GEMM + fused dual top-2, 256x256 tile ----------------
// Theory (R9 post-mortem): every structure R1..R9 moved staged-LDS bytes at a
// ~2 TB/s wall regardless of pipeline depth -> time == staged_bytes / 2TB/s.
// 256x256 tile HALVES staged bytes: total 2.36 GB (was 4.72).
// grid (48,16), XCD-bijective remap; 512 thr / 8 waves; wave (wr=w&1,wc=w>>1)
// owns 128x64 = 8x4 16x16 frags; acc[8][4] f32x4 = 128 VGPR; cap 256 (512,2).
// BK=32 per step, 48 steps, depth-1 reg-staged with raw barriers (R9 KSTEP).
// LDS: dbuf 2x64KB tiles + rowW[4][256] + colW[2][256] + ia/ib = 154 KB dyn.
__global__ __launch_bounds__(512, 2)
void sim_top2_mfma() {
  extern __shared__ char smem[];
  char* const SMb = smem;                              // [2][A|B][32 KB] tiles
  Top2* const rowW = (Top2*)(smem + 131072);           // [4 wc][256 rows]
  Top2* const colW = (Top2*)(smem + 131072 + 16384);   // [2 wr][256 cols]
  float* const iaS = (float*)(smem + 131072 + 16384 + 8192);  // [256]
  float* const ibS = iaS + 256;                        // [256]

  const int q = blockIdx.x;                            // 0..47
  const int itile = (q & 7) * 6 + (q >> 3);            // XCD-local, bijective
  const int slice = blockIdx.y;                        // 0..15
  const int i0 = itile * TI2;
  const int tid = threadIdx.x;
  const int wave = tid >> 6, lane = tid & 63;
  const int wr = wave & 1, wc = wave >> 1;             // 2 x 4 wave grid
  const int fr = lane & 15, kq = lane >> 4;
  const int jtb = slice * JT2;

  // staging: waves 0-3 stage A, 4-7 stage B; 128 B/thread, 8 x 16 B chunks
  const int side = wave >> 2;
  const int tid2 = tid & 255;
  const char* opBase = (const char*)(side ? g_BT : g_AT);

  uint4 s0, s1, s2, s3, s4, s5, s6, s7;                // NAMED staging regs
  auto issue = [&](int t) {                            // load batch t
    const int gg = t & 15;
    const size_t rb = side ? (size_t)(jtb + (t >> 4)) * TI2 : (size_t)i0;
    const char* base = opBase + ((size_t)gg * N + rb) * 128 + tid2 * 16;
    s0 = *reinterpret_cast<const uint4*>(base);
    s1 = *reinterpret_cast<const uint4*>(base + 4096);
    s2 = *reinterpret_cast<const uint4*>(base + 8192);
    s3 = *reinterpret_cast<const uint4*>(base + 12288);
    s4 = *reinterpret_cast<const uint4*>(base + 16384);
    s5 = *reinterpret_cast<const uint4*>(base + 20480);
    s6 = *reinterpret_cast<const uint4*>(base + 24576);
    s7 = *reinterpret_cast<const uint4*>(base + 28672);
  };

  issue(0);                                            // prologue batch

  if (tid < 256) {
    iaS[tid] = g_invA[i0 + tid];
    Top2 z; z.v0 = -1e30f; z.v1 = -1e30f; z.i0 = 0x7fffffff; z.i1 = 0x7fffffff;
#pragma unroll
    for (int w = 0; w < 4; ++w) rowW[w * 256 + tid] = z;
  }
  __syncthreads();                                     // init visible

  // loop-invariant LDS fragment byte offsets (logical chunk ^ (row&7))
  const int f7 = fr & 7;
  const int cHi = (kq ^ f7) << 4;
  const int cLo = ((kq + 4) ^ f7) << 4;
  const int aOff0 = (wr * 128 + fr) * 128;             // + mi*2048
  const int bOff0 = (wc * 64 + fr) * 128;              // + ni*2048
  char* const wbase0 = SMb + side * 32768 + tid2 * 16; // + parity*65536

  int t = 0;
  for (int jt = jtb; jt < jtb + JT2; ++jt) {
    const int j0 = jt * TI2;
    if (tid < 256) ibS[tid] = g_invB[j0 + tid];

    f32x4 acc[8][4];
#pragma unroll
    for (int mi = 0; mi < 8; ++mi)
#pragma unroll
      for (int ni = 0; ni < 4; ++ni)
#pragma unroll
        for (int e = 0; e < 4; ++e) acc[mi][ni][e] = 0.f;

    for (int g = 0; g < GPJ; ++g, ++t) {
      const int par = t & 1;
      __builtin_amdgcn_s_barrier();                    // B1: buf[par] consumed
      asm volatile("" ::: "memory");
      {                                                // write batch t (compiler
        char* wb = wbase0 + par * 65536;               //  waits its vmcnt here)
        *reinterpret_cast<uint4*>(wb)          = s0;
        *reinterpret_cast<uint4*>(wb + 4096)   = s1;
        *reinterpret_cast<uint4*>(wb + 8192)   = s2;
        *reinterpret_cast<uint4*>(wb + 12288)  = s3;
        *reinterpret_cast<uint4*>(wb + 16384)  = s4;
        *reinterpret_cast<uint4*>(wb + 20480)  = s5;
        *reinterpret_cast<uint4*>(wb + 24576)  = s6;
        *reinterpret_cast<uint4*>(wb + 28672)  = s7;
      }
      if (t + 1 < NSTEP2) issue(t + 1);                // t+1 flies over compute
      asm volatile("s_waitcnt lgkmcnt(0)" ::: "memory");
      __builtin_amdgcn_s_barrier();                    // B2: tile t visible
      __builtin_amdgcn_sched_barrier(0);               // pin ds_reads (rule #18)

      const char* bA = SMb + par * 65536;
      const char* bB = bA + 32768;
#pragma unroll
      for (int h = 0; h < 2; ++h) {                    // two mi-halves: caps regs
        f16x8 ah[4], al[4];
#pragma unroll
        for (int m = 0; m < 4; ++m) {
          const char* pa = bA + aOff0 + (h * 4 + m) * 2048;
          ah[m] = *reinterpret_cast<const f16x8*>(pa + cHi);
          al[m] = *reinterpret_cast<const f16x8*>(pa + cLo);
        }
#pragma unroll
        for (int ni = 0; ni < 4; ++ni) {
          const char* pb = bB + bOff0 + ni * 2048;
          f16x8 bh = *reinterpret_cast<const f16x8*>(pb + cHi);
          f16x8 bl = *reinterpret_cast<const f16x8*>(pb + cLo);
#pragma unroll
          for (int m = 0; m < 4; ++m) {
            acc[h*4+m][ni] = __builtin_amdgcn_mfma_f32_16x16x32_f16(ah[m], bh, acc[h*4+m][ni], 0, 0, 0);
            acc[h*4+m][ni] = __builtin_amdgcn_mfma_f32_16x16x32_f16(ah[m], bl, acc[h*4+m][ni], 0, 0, 0);
            acc[h*4+m][ni] = __builtin_amdgcn_mfma_f32_16x16x32_f16(al[m], bh, acc[h*4+m][ni], 0, 0, 0);
          }
        }
      }
      asm volatile("" ::: "memory");
    }

    // ---- epilogue: scale to cosine sims (C layout: col=fr, row=kq*4+e) ----
    // (next j-tile's first batch is in flight under this work)
    float ib[4];
#pragma unroll
    for (int ni = 0; ni < 4; ++ni) ib[ni] = ibS[wc * 64 + ni * 16 + fr];
#pragma unroll
    for (int mi = 0; mi < 8; ++mi)
#pragma unroll
      for (int e = 0; e < 4; ++e) {
        const float iar = iaS[wr * 128 + mi * 16 + kq * 4 + e];
#pragma unroll
        for (int ni = 0; ni < 4; ++ni)
          acc[mi][ni][e] *= iar * ib[ni];
      }

    // ---- row top-2 (4 ni in-thread, then 16 fr lanes; owner fr==0) ----
#pragma unroll
    for (int mi = 0; mi < 8; ++mi) {
#pragma unroll
      for (int e = 0; e < 4; ++e) {
        const int row = wr * 128 + mi * 16 + kq * 4 + e;
        float v0 = -1e30f, v1 = -1e30f; int id0 = 0x7fffffff, id1 = 0x7fffffff;
#pragma unroll
        for (int ni = 0; ni < 4; ++ni)
          t2_ins(acc[mi][ni][e], j0 + wc * 64 + ni * 16 + fr, v0, id0, v1, id1);
#pragma unroll
        for (int m = 1; m < 16; m <<= 1) {
          float ov0 = __shfl_xor(v0, m), ov1 = __shfl_xor(v1, m);
          int oi0 = __shfl_xor(id0, m), oi1 = __shfl_xor(id1, m);
          t2_ins(ov0, oi0, v0, id0, v1, id1);
          t2_ins(ov1, oi1, v0, id0, v1, id1);
        }
        if (fr == 0) {                      // unique (wave,kq,mi,e) owner
          Top2 tT = rowW[wc * 256 + row];
          t2_ins(v0, id0, tT.v0, tT.i0, tT.v1, tT.i1);
          t2_ins(v1, id1, tT.v0, tT.i0, tT.v1, tT.i1);
          rowW[wc * 256 + row] = tT;
        }
      }
    }

    // ---- col top-2 (32 rows in-thread, then across kq; owner kq==0) ----
#pragma unroll
    for (int ni = 0; ni < 4; ++ni) {
      float v0 = -1e30f, v1 = -1e30f; int id0 = 0x7fffffff, id1 = 0x7fffffff;
#pragma unroll
      for (int mi = 0; mi < 8; ++mi)
#pragma unroll
        for (int e = 0; e < 4; ++e)
          t2_ins(acc[mi][ni][e], i0 + wr * 128 + mi * 16 + kq * 4 + e, v0, id0, v1, id1);
#pragma unroll
      for (int m = 16; m < 64; m <<= 1) {
        float ov0 = __shfl_xor(v0, m), ov1 = __shfl_xor(v1, m);
        int oi0 = __shfl_xor(id0, m), oi1 = __shfl_xor(id1, m);
        t2_ins(ov0, oi0, v0, id0, v1, id1);
        t2_ins(ov1, oi1, v0, id0, v1, id1);
      }
      if (kq == 0) {
        Top2 tT; tT.v0 = v0; tT.v1 = v1; tT.i0 = id0; tT.i1 = id1;
        colW[wr * 256 + wc * 64 + ni * 16 + fr] = tT;
      }
    }
    __syncthreads();                        // colW visible
    if (tid < 256) {
      Top2 tT = colW[tid];
      Top2 o  = colW[256 + tid];
      t2_ins(o.v0, o.i0, tT.v0, tT.i0, tT.v1, tT.i1);
      t2_ins(o.v1, o.i1, tT.v0, tT.i0, tT.v1, tT.i1);
      g_cpart[itile][j0 + tid] = tT;
    }
  }

  __syncthreads();
  if (tid < 256) {
    Top2 tT = rowW[tid];
#pragma unroll
    for (int w = 1; w < 4; ++w) {
      Top2 o = rowW[w * 256 + tid];
      t2_ins(o.v0, o.i0, tT.v0, tT.i0, tT.v1, tT.i1);
      t2_ins(o.v1, o.i1, tT.v0, tT.i0, tT.v1, tT.i1);
    }
    g_rpart[slice][i0 + tid] = tT;
  }
}

// ---------------- kernel 3: merge partials ----------------
__global__ void merge_kernel() {
  int i = blockIdx.x * 256 + threadIdx.x;
  if (i >= N) return;
  {
    float v0 = -1e30f, v1 = -1e30f; int id0 = 0x7fffffff, id1 = 0x7fffffff;
#pragma unroll
    for (int s = 0; s < NS2; ++s) {
      Top2 p = g_rpart[s][i];
      t2_ins(p.v0, p.i0, v0, id0, v1, id1);
      t2_ins(p.v1, p.i1, v0, id0, v1, id1);
    }
    float d0 = 2.f - 2.f * v0, d1 = 2.f - 2.f * v1;
    g_nn12[i] = id0; g_r12[i] = d0 / (d1 + 1e-8f); g_sim0[i] = v0;
  }
  {
    float v0 = -1e30f, v1 = -1e30f; int id0 = 0x7fffffff, id1 = 0x7fffffff;
    for (int it = 0; it < NT2; ++it) {
      Top2 p = g_cpart[it][i];
      t2_ins(p.v0, p.i0, v0, id0, v1, id1);
      t2_ins(p.v1, p.i1, v0, id0, v1, id1);
    }
    float d0 = 2.f - 2.f * v0, d1 = 2.f - 2.f * v1;
    g_nn21[i] = id0; g_r21[i] = d0 / (d1 + 1e-8f);
  }
}

// ---------------- kernel 4: mutual-NN + ratio mask, outputs ----------------
__global__ void finalize_kernel(float* __restrict__ out) {
  int i = blockIdx.x * 256 + threadIdx.x;
  if (i >= N) return;
  int j = g_nn12[i];
  int jc = j < 0 ? 0 : (j >= N ? N - 1 : j);
  bool mask = (g_nn21[jc] == i) && (g_r12[i] <= 0.95f) && (g_r21[jc] <= 0.95f);
  out[i]         = bf16_quant(mask ? g_sim0[i] : 0.f);
  out[N + i]     = bf16_quant((float)j);
  out[2 * N + i] = mask ? 1.f : 0.f;
}

extern "C" void kernel_launch(void* const* d_in, const int* in_sizes, int n_in,
                              void* d_out, int out_size, void* d_ws, size_t ws_size,
                              hipStream_t stream) {
  const float* A = (const float*)d_in[0];  // fp32, channel-major [CH][N]
  const float* B = (const float*)d_in[1];
  (void)d_ws; (void)ws_size;

  static bool attr_done = false;
  if (!attr_done) {
    hipFuncSetAttribute(reinterpret_cast<const void*>(sim_top2_mfma),
                        hipFuncAttributeMaxDynamicSharedMemorySize, DSMEM_BYTES);
    attr_done = true;
  }

  prep_kernel<<<dim3(192, 2), 256, 0, stream>>>(A, B);
  sim_top2_mfma<<<dim3(NT2, NS2), 512, DSMEM_BYTES, stream>>>();
  merge_kernel<<<dim3((N + 255) / 256), 256, 0, stream>>>();
  finalize_kernel<<<dim3((N + 255) / 256), 256, 0, stream>>>((float*)d_out);
}